// Round 7
// baseline (200.805 us; speedup 1.0000x reference)
//
#include <hip/hip_runtime.h>
#include <hip/hip_bf16.h>
#include <math.h>

typedef __attribute__((ext_vector_type(8))) short bf16x8;
typedef __attribute__((ext_vector_type(4))) float f32x4;

#define MFMA16 __builtin_amdgcn_mfma_f32_16x16x32_bf16

static constexpr int TSEQ = 4096;
static constexpr int EMB = 1024;
static constexpr int HD = 64;

__device__ __forceinline__ unsigned short f2bf(float f) {
    unsigned u = __builtin_bit_cast(unsigned, f);
    u += 0x7fffu + ((u >> 16) & 1u);
    return (unsigned short)(u >> 16);
}
__device__ __forceinline__ int pk2bf(float a, float b) {
    return (int)((unsigned)f2bf(a) | ((unsigned)f2bf(b) << 16));
}

union frag_u { int i[4]; bf16x8 v; };

// Pack W -> Wp[kc=16][n=192][64k] bf16 (linear; LDS swizzle applied at ds_write
// time in proj). Wq pre-scaled by 1/sqrt(1024).
__global__ void prep_w(const float* __restrict__ Wq, const float* __restrict__ Wk,
                       const float* __restrict__ Wv, unsigned short* __restrict__ Wp) {
    int id = blockIdx.x * 256 + threadIdx.x;        // 0..196607
    int wsel = id >> 16;
    int t = id & 65535;                             // = k*64 + n0 (coalesced read)
    int k = t >> 6, n0 = t & 63;
    const float* W = (wsel == 0) ? Wq : (wsel == 1) ? Wk : Wv;
    float v = W[t];
    if (wsel == 0) v *= 0.03125f;                   // 1/sqrt(1024)
    int n = wsel * 64 + n0;
    Wp[(k >> 6) * 12288 + n * 64 + (k & 63)] = f2bf(v);
}

// Projection v5: 512 blocks x 256 thr, block = 32 rows x 192 cols, BK=64,
// 16 iterations. TRUE software pipeline: chunk k+2's global loads issued at
// iter k, ds-written at iter k+1, consumed at iter k+2 -> every load gets a
// full iteration of latency cover. Raw lgkm-only barrier keeps global loads
// in flight across it. W staged once per block into LDS (shared by all 4
// waves); XOR piece-swizzle gives conflict-free b128 reads/writes.
__global__ __launch_bounds__(256, 2) void proj_kernel(const float* __restrict__ X,
        const unsigned short* __restrict__ Wp, unsigned short* __restrict__ Qp,
        unsigned short* __restrict__ Kp, unsigned short* __restrict__ Vp) {
    // per buffer: W rows 0..191 (64 shorts each), X rows 192..223. 56 KB total.
    __shared__ unsigned short sb[2][224 * 64];
    const int tid = threadIdx.x;
    const int lane = tid & 63, wave = tid >> 6;     // wave = col-quarter
    const int col = lane & 15, quad = lane >> 4;
    const int row0 = blockIdx.x * 32;

    // X staging: thread t -> row t>>3, piece t&7 (8 fp32 -> 8 bf16 = 16 B)
    const int xrow = tid >> 3, xpc = tid & 7;
    const float* xg = X + (size_t)(row0 + xrow) * EMB + xpc * 8;
    const int xw_off = (192 + xrow) * 64 + ((xpc ^ (xrow & 7)) * 8);

    uint4 wreg[2][6];
    float4 xa[2], xb[2];

    auto load_chunk = [&](int kc, int s) {
        const unsigned short* wg = Wp + kc * 12288;
#pragma unroll
        for (int i = 0; i < 6; i++)
            wreg[s][i] = *(const uint4*)(wg + (i * 256 + tid) * 8);
        const float* xp = xg + kc * 64;
        xa[s] = *(const float4*)(xp);
        xb[s] = *(const float4*)(xp + 4);
    };
    auto write_chunk = [&](int s, int buf) {
        unsigned short* b = &sb[buf][0];
#pragma unroll
        for (int i = 0; i < 6; i++) {
            const int idx = i * 256 + tid;
            const int n = idx >> 3, p = idx & 7;
            *(uint4*)&b[n * 64 + ((p ^ (n & 7)) * 8)] = wreg[s][i];
        }
        frag_u u;
        u.i[0] = pk2bf(xa[s].x, xa[s].y); u.i[1] = pk2bf(xa[s].z, xa[s].w);
        u.i[2] = pk2bf(xb[s].x, xb[s].y); u.i[3] = pk2bf(xb[s].z, xb[s].w);
        *(bf16x8*)&b[xw_off] = u.v;
    };

    f32x4 acc[2][3];
#pragma unroll
    for (int af = 0; af < 2; af++)
#pragma unroll
        for (int cf = 0; cf < 3; cf++) acc[af][cf] = (f32x4)(0.0f);

    // prologue: chunk 0 staged, chunk 1 in flight
    load_chunk(0, 0);
    write_chunk(0, 0);
    load_chunk(1, 1);
    asm volatile("s_waitcnt lgkmcnt(0)\ns_barrier" ::: "memory");

    for (int kc = 0; kc < 16; kc++) {
        const int buf = kc & 1;
        if (kc < 15) write_chunk((kc + 1) & 1, buf ^ 1);  // arrived 1 iter ago
        if (kc < 14) load_chunk(kc + 2, kc & 1);          // consumed in 2 iters
        const unsigned short* b = &sb[buf][0];
#pragma unroll
        for (int j = 0; j < 2; j++) {
            const int v = j * 4 + quad;
            bf16x8 a[2], w[3];
#pragma unroll
            for (int af = 0; af < 2; af++) {
                const int r = af * 16 + col;
                a[af] = *(const bf16x8*)&b[(192 + r) * 64 + ((v ^ (r & 7)) * 8)];
            }
#pragma unroll
            for (int cf = 0; cf < 3; cf++) {
                const int n = wave * 48 + cf * 16 + col;
                w[cf] = *(const bf16x8*)&b[n * 64 + ((v ^ (n & 7)) * 8)];
            }
#pragma unroll
            for (int af = 0; af < 2; af++)
#pragma unroll
                for (int cf = 0; cf < 3; cf++)
                    acc[af][cf] = MFMA16(a[af], w[cf], acc[af][cf], 0, 0, 0);
        }
        if (kc < 15)
            asm volatile("s_waitcnt lgkmcnt(0)\ns_barrier" ::: "memory");
    }

    // epilogue: wave-uniform dispatch to packed Q/K/V layouts
    const int c = blockIdx.x;
#pragma unroll
    for (int af = 0; af < 2; af++) {
        const int tile = c * 2 + af;
        const int j = af;
#pragma unroll
        for (int cf = 0; cf < 3; cf++) {
            const int n0 = wave * 48 + cf * 16;
            if (n0 < 64) {
                const int t = n0 >> 4;
#pragma unroll
                for (int r = 0; r < 4; r++)
                    Qp[tile * 1024 + (t >> 1) * 512 + (quad * 4 + r) * 32 +
                       ((t & 1) * 2 + (col >> 3)) * 8 + (col & 7)] = f2bf(acc[af][cf][r]);
            } else if (n0 < 128) {
                const int tt = (n0 - 64) >> 4;
#pragma unroll
                for (int r = 0; r < 4; r++)
                    Kp[((c * 2 + j) * 2 + (tt >> 1)) * 512 + (quad * 4 + r) * 32 +
                       ((tt & 1) * 2 + (col >> 3)) * 8 + (col & 7)] = f2bf(acc[af][cf][r]);
            } else {
                const int t4 = (n0 - 128) >> 4;
                ushort4 pk;
                pk.x = f2bf(acc[af][cf][0]); pk.y = f2bf(acc[af][cf][1]);
                pk.z = f2bf(acc[af][cf][2]); pk.w = f2bf(acc[af][cf][3]);
                *(ushort4*)&Vp[c * 2048 + t4 * 512 + col * 32 + j * 16 + quad * 4] = pk;
            }
        }
    }
}

// Flash attention (known-good R4 version): 512 blocks x 512 threads (8 waves),
// block = (batch, 32-row q-tile) heavy-first. Chunks split 8 ways (fixed m=0
// partials additive); staged LDS tree reduction at the end.
__global__ __launch_bounds__(512, 4) void attn_kernel(const unsigned short* __restrict__ Qp,
        const unsigned short* __restrict__ Kp, const unsigned short* __restrict__ Vp,
        float* __restrict__ Out) {
    __shared__ float cmb[4][2][64][20];            // 40 KB
    __shared__ unsigned short plds[8][2][640];     // 20 KB
    const int lane = threadIdx.x & 63, wave = threadIdx.x >> 6;
    const int col = lane & 15, quad = lane >> 4;
    const int batch = blockIdx.x & 3;
    const int ti = 127 - (blockIdx.x >> 2);
    const int q0 = ti * 32;
    const size_t bT = (size_t)batch * TSEQ;
    const int fragoff = col * 64 + quad * 16;

    const char* QpB = (const char*)Qp;
    const char* KpB = (const char*)Kp;
    const char* VpB = (const char*)Vp;
    const int gt = (int)((bT + q0) >> 4);
    const int c0 = (int)(bT >> 5);

    bf16x8 aq[2][2];
#pragma unroll
    for (int m = 0; m < 2; m++)
#pragma unroll
        for (int h = 0; h < 2; h++)
            aq[m][h] = *(const bf16x8*)(QpB + (size_t)((gt + m) * 2 + h) * 1024 + fragoff);

    f32x4 o[2][4];
    f32x4 lsum[2];
#pragma unroll
    for (int m = 0; m < 2; m++) {
        lsum[m] = (f32x4)(0.0f);
#pragma unroll
        for (int t = 0; t < 4; t++) o[m][t] = (f32x4)(0.0f);
    }

    for (int c = wave; c <= ti; c += 8) {
        const char* kb = KpB + (size_t)(c0 + c) * 4096;
        const char* vb = VpB + (size_t)(c0 + c) * 4096;
        bf16x8 bk[2][2], bv[4];
#pragma unroll
        for (int j = 0; j < 2; j++)
#pragma unroll
            for (int h = 0; h < 2; h++)
                bk[j][h] = *(const bf16x8*)(kb + j * 2048 + h * 1024 + fragoff);
#pragma unroll
        for (int t = 0; t < 4; t++)
            bv[t] = *(const bf16x8*)(vb + t * 1024 + fragoff);

        f32x4 s[2][2];
#pragma unroll
        for (int m = 0; m < 2; m++)
#pragma unroll
            for (int j = 0; j < 2; j++) {
                f32x4 a = MFMA16(aq[m][0], bk[j][0], (f32x4)(0.0f), 0, 0, 0);
                s[m][j] = MFMA16(aq[m][1], bk[j][1], a, 0, 0, 0);
            }
        const bool diag = (c == ti);
#pragma unroll
        for (int m = 0; m < 2; m++)
#pragma unroll
            for (int j = 0; j < 2; j++)
#pragma unroll
                for (int r = 0; r < 4; r++) {
                    float v = s[m][j][r];
                    if (diag && (j * 16 + col > m * 16 + quad * 4 + r)) v = -INFINITY;
                    const float p = __expf(v);   // |score| small: safe without max-sub
                    lsum[m][r] += p;
                    plds[wave][m][(quad * 4 + r) * 40 + j * 16 + col] =
                        (unsigned short)(__builtin_bit_cast(unsigned, p) >> 16);
                }
        bf16x8 pa[2];
#pragma unroll
        for (int m = 0; m < 2; m++)
            pa[m] = *(const bf16x8*)(&plds[wave][m][col * 40 + quad * 8]);
#pragma unroll
        for (int m = 0; m < 2; m++)
#pragma unroll
            for (int t = 0; t < 4; t++)
                o[m][t] = MFMA16(pa[m], bv[t], o[m][t], 0, 0, 0);
    }

    // staged tree reduction: 8 -> 4 -> 2 -> 1 partials
    auto wr = [&](int s) {
#pragma unroll
        for (int m = 0; m < 2; m++) {
#pragma unroll
            for (int t = 0; t < 4; t++)
                *(f32x4*)&cmb[s][m][lane][t * 4] = o[m][t];
            *(f32x4*)&cmb[s][m][lane][16] = lsum[m];
        }
    };
    auto rd = [&](int s) {
#pragma unroll
        for (int m = 0; m < 2; m++) {
#pragma unroll
            for (int t = 0; t < 4; t++)
                o[m][t] += *(const f32x4*)&cmb[s][m][lane][t * 4];
            lsum[m] += *(const f32x4*)&cmb[s][m][lane][16];
        }
    };
    if (wave >= 4) wr(wave - 4);
    __syncthreads();
    if (wave < 4) rd(wave);
    __syncthreads();
    if (wave == 2 || wave == 3) wr(wave);
    __syncthreads();
    if (wave < 2) rd(wave + 2);
    __syncthreads();
    if (wave == 1) wr(1);
    __syncthreads();
    if (wave == 0) {
        rd(1);
#pragma unroll
        for (int off = 1; off < 16; off <<= 1)
#pragma unroll
            for (int m = 0; m < 2; m++)
#pragma unroll
                for (int r = 0; r < 4; r++)
                    lsum[m][r] += __shfl_xor(lsum[m][r], off, 64);
#pragma unroll
        for (int m = 0; m < 2; m++)
#pragma unroll
            for (int r = 0; r < 4; r++) {
                const float inv = 1.0f / lsum[m][r];
                const size_t orow = (bT + q0 + m * 16 + quad * 4 + r) * HD;
#pragma unroll
                for (int t = 0; t < 4; t++)
                    Out[orow + t * 16 + col] = o[m][t][r] * inv;
            }
    }
}

extern "C" void kernel_launch(void* const* d_in, const int* in_sizes, int n_in,
                              void* d_out, int out_size, void* d_ws, size_t ws_size,
                              hipStream_t stream) {
    const float* x  = (const float*)d_in[0];
    const float* Wq = (const float*)d_in[1];
    const float* Wk = (const float*)d_in[2];
    const float* Wv = (const float*)d_in[3];
    float* out = (float*)d_out;

    char* w = (char*)d_ws;
    unsigned short* Wp = (unsigned short*)(w);                            // 384 KB
    unsigned short* Qp = (unsigned short*)(w + (512 << 10));              // 2 MB
    unsigned short* Kp = (unsigned short*)(w + (512 << 10) + (2 << 20));  // 2 MB
    unsigned short* Vp = (unsigned short*)(w + (512 << 10) + (4 << 20));  // 2 MB

    hipLaunchKernelGGL(prep_w, dim3(768), dim3(256), 0, stream, Wq, Wk, Wv, Wp);
    hipLaunchKernelGGL(proj_kernel, dim3(512), dim3(256), 0, stream, x, Wp, Qp, Kp, Vp);
    hipLaunchKernelGGL(attn_kernel, dim3(512), dim3(512), 0, stream, Qp, Kp, Vp, out);
}

// Round 8
// 180.378 us; speedup vs baseline: 1.1132x; 1.1132x over previous
//
#include <hip/hip_runtime.h>
#include <hip/hip_bf16.h>
#include <math.h>

typedef __attribute__((ext_vector_type(8))) short bf16x8;
typedef __attribute__((ext_vector_type(4))) float f32x4;

#define MFMA16 __builtin_amdgcn_mfma_f32_16x16x32_bf16

static constexpr int TSEQ = 4096;
static constexpr int EMB = 1024;
static constexpr int HD = 64;

__device__ __forceinline__ unsigned short f2bf(float f) {
    unsigned u = __builtin_bit_cast(unsigned, f);
    u += 0x7fffu + ((u >> 16) & 1u);
    return (unsigned short)(u >> 16);
}
__device__ __forceinline__ int pk2bf(float a, float b) {
    return (int)((unsigned)f2bf(a) | ((unsigned)f2bf(b) << 16));
}

union frag_u { int i[4]; bf16x8 v; };

// Pack W -> Wp[kc=16][n=192][64k] bf16 (linear; LDS swizzle applied at ds_write
// time in proj). Wq pre-scaled by 1/sqrt(1024).
__global__ void prep_w(const float* __restrict__ Wq, const float* __restrict__ Wk,
                       const float* __restrict__ Wv, unsigned short* __restrict__ Wp) {
    int id = blockIdx.x * 256 + threadIdx.x;        // 0..196607
    int wsel = id >> 16;
    int t = id & 65535;                             // = k*64 + n0 (coalesced read)
    int k = t >> 6, n0 = t & 63;
    const float* W = (wsel == 0) ? Wq : (wsel == 1) ? Wk : Wv;
    float v = W[t];
    if (wsel == 0) v *= 0.03125f;                   // 1/sqrt(1024)
    int n = wsel * 64 + n0;
    Wp[(k >> 6) * 12288 + n * 64 + (k & 63)] = f2bf(v);
}

// Projection v6: 512 blocks x 256 thr, block = 32 rows x 192 cols, BK=64.
// 2-deep software pipeline with STATIC register slots (R7's runtime slot
// index demoted staging regs to scratch: 160 MB WRITE_SIZE). K-loop unrolled
// by 2 so all slot/buffer indices are literals. Raw lgkm-only barrier keeps
// global loads in flight across it. W staged in LDS, shared by all 4 waves.
__global__ __launch_bounds__(256, 2) void proj_kernel(const float* __restrict__ X,
        const unsigned short* __restrict__ Wp, unsigned short* __restrict__ Qp,
        unsigned short* __restrict__ Kp, unsigned short* __restrict__ Vp) {
    // per buffer: W rows 0..191 (64 shorts each), X rows 192..223. 56 KB total.
    __shared__ unsigned short sb[2][224 * 64];
    const int tid = threadIdx.x;
    const int lane = tid & 63, wave = tid >> 6;     // wave = col-quarter
    const int col = lane & 15, quad = lane >> 4;
    const int row0 = blockIdx.x * 32;

    // X staging: thread t -> row t>>3, piece t&7 (8 fp32 -> 8 bf16 = 16 B)
    const int xrow = tid >> 3, xpc = tid & 7;
    const float* xg = X + (size_t)(row0 + xrow) * EMB + xpc * 8;
    const int xw_off = (192 + xrow) * 64 + ((xpc ^ (xrow & 7)) * 8);

    // two static staging slots — never runtime-indexed
    uint4 wreg0[6], wreg1[6];
    float4 xa0, xb0, xa1, xb1;

    auto load0 = [&](int kc) {
        const unsigned short* wg = Wp + kc * 12288;
#pragma unroll
        for (int i = 0; i < 6; i++)
            wreg0[i] = *(const uint4*)(wg + (i * 256 + tid) * 8);
        const float* xp = xg + kc * 64;
        xa0 = *(const float4*)(xp);
        xb0 = *(const float4*)(xp + 4);
    };
    auto load1 = [&](int kc) {
        const unsigned short* wg = Wp + kc * 12288;
#pragma unroll
        for (int i = 0; i < 6; i++)
            wreg1[i] = *(const uint4*)(wg + (i * 256 + tid) * 8);
        const float* xp = xg + kc * 64;
        xa1 = *(const float4*)(xp);
        xb1 = *(const float4*)(xp + 4);
    };
    auto write0 = [&](unsigned short* b) {
#pragma unroll
        for (int i = 0; i < 6; i++) {
            const int idx = i * 256 + tid;
            const int n = idx >> 3, p = idx & 7;
            *(uint4*)&b[n * 64 + ((p ^ (n & 7)) * 8)] = wreg0[i];
        }
        frag_u u;
        u.i[0] = pk2bf(xa0.x, xa0.y); u.i[1] = pk2bf(xa0.z, xa0.w);
        u.i[2] = pk2bf(xb0.x, xb0.y); u.i[3] = pk2bf(xb0.z, xb0.w);
        *(bf16x8*)&b[xw_off] = u.v;
    };
    auto write1 = [&](unsigned short* b) {
#pragma unroll
        for (int i = 0; i < 6; i++) {
            const int idx = i * 256 + tid;
            const int n = idx >> 3, p = idx & 7;
            *(uint4*)&b[n * 64 + ((p ^ (n & 7)) * 8)] = wreg1[i];
        }
        frag_u u;
        u.i[0] = pk2bf(xa1.x, xa1.y); u.i[1] = pk2bf(xa1.z, xa1.w);
        u.i[2] = pk2bf(xb1.x, xb1.y); u.i[3] = pk2bf(xb1.z, xb1.w);
        *(bf16x8*)&b[xw_off] = u.v;
    };

    f32x4 acc[2][3];
#pragma unroll
    for (int af = 0; af < 2; af++)
#pragma unroll
        for (int cf = 0; cf < 3; cf++) acc[af][cf] = (f32x4)(0.0f);

    auto compute = [&](const unsigned short* b) {
#pragma unroll
        for (int j = 0; j < 2; j++) {
            const int v = j * 4 + quad;
            bf16x8 a[2], w[3];
#pragma unroll
            for (int af = 0; af < 2; af++) {
                const int r = af * 16 + col;
                a[af] = *(const bf16x8*)&b[(192 + r) * 64 + ((v ^ (r & 7)) * 8)];
            }
#pragma unroll
            for (int cf = 0; cf < 3; cf++) {
                const int n = wave * 48 + cf * 16 + col;
                w[cf] = *(const bf16x8*)&b[n * 64 + ((v ^ (n & 7)) * 8)];
            }
#pragma unroll
            for (int af = 0; af < 2; af++)
#pragma unroll
                for (int cf = 0; cf < 3; cf++)
                    acc[af][cf] = MFMA16(a[af], w[cf], acc[af][cf], 0, 0, 0);
        }
    };

#define LGKM_BARRIER() asm volatile("s_waitcnt lgkmcnt(0)\ns_barrier" ::: "memory")

    // prologue: chunk 0 staged into buf0, chunk 1 in flight (slot1)
    load0(0);
    write0(&sb[0][0]);
    load1(1);
    LGKM_BARRIER();

    // iter kc: write chunk kc+1 (slot (kc+1)&1) -> buf (kc+1)&1; issue load of
    // chunk kc+2 into slot kc&1; compute chunk kc from buf kc&1.
    for (int k = 0; k < 16; k += 2) {
        // even iter k
        if (k < 15) write1(&sb[1][0]);
        if (k < 14) load0(k + 2);
        compute(&sb[0][0]);
        LGKM_BARRIER();
        // odd iter k+1
        if (k < 14) write0(&sb[0][0]);
        if (k < 13) load1(k + 3);
        compute(&sb[1][0]);
        if (k < 14) LGKM_BARRIER();
    }
#undef LGKM_BARRIER

    // epilogue: wave-uniform dispatch to packed Q/K/V layouts
    const int c = blockIdx.x;
#pragma unroll
    for (int af = 0; af < 2; af++) {
        const int tile = c * 2 + af;
        const int j = af;
#pragma unroll
        for (int cf = 0; cf < 3; cf++) {
            const int n0 = wave * 48 + cf * 16;
            if (n0 < 64) {
                const int t = n0 >> 4;
#pragma unroll
                for (int r = 0; r < 4; r++)
                    Qp[tile * 1024 + (t >> 1) * 512 + (quad * 4 + r) * 32 +
                       ((t & 1) * 2 + (col >> 3)) * 8 + (col & 7)] = f2bf(acc[af][cf][r]);
            } else if (n0 < 128) {
                const int tt = (n0 - 64) >> 4;
#pragma unroll
                for (int r = 0; r < 4; r++)
                    Kp[((c * 2 + j) * 2 + (tt >> 1)) * 512 + (quad * 4 + r) * 32 +
                       ((tt & 1) * 2 + (col >> 3)) * 8 + (col & 7)] = f2bf(acc[af][cf][r]);
            } else {
                const int t4 = (n0 - 128) >> 4;
                ushort4 pk;
                pk.x = f2bf(acc[af][cf][0]); pk.y = f2bf(acc[af][cf][1]);
                pk.z = f2bf(acc[af][cf][2]); pk.w = f2bf(acc[af][cf][3]);
                *(ushort4*)&Vp[c * 2048 + t4 * 512 + col * 32 + j * 16 + quad * 4] = pk;
            }
        }
    }
}

// Flash attention (known-good R4 version): 512 blocks x 512 threads (8 waves),
// block = (batch, 32-row q-tile) heavy-first. Chunks split 8 ways (fixed m=0
// partials additive); staged LDS tree reduction at the end.
__global__ __launch_bounds__(512, 4) void attn_kernel(const unsigned short* __restrict__ Qp,
        const unsigned short* __restrict__ Kp, const unsigned short* __restrict__ Vp,
        float* __restrict__ Out) {
    __shared__ float cmb[4][2][64][20];            // 40 KB
    __shared__ unsigned short plds[8][2][640];     // 20 KB
    const int lane = threadIdx.x & 63, wave = threadIdx.x >> 6;
    const int col = lane & 15, quad = lane >> 4;
    const int batch = blockIdx.x & 3;
    const int ti = 127 - (blockIdx.x >> 2);
    const int q0 = ti * 32;
    const size_t bT = (size_t)batch * TSEQ;
    const int fragoff = col * 64 + quad * 16;

    const char* QpB = (const char*)Qp;
    const char* KpB = (const char*)Kp;
    const char* VpB = (const char*)Vp;
    const int gt = (int)((bT + q0) >> 4);
    const int c0 = (int)(bT >> 5);

    bf16x8 aq[2][2];
#pragma unroll
    for (int m = 0; m < 2; m++)
#pragma unroll
        for (int h = 0; h < 2; h++)
            aq[m][h] = *(const bf16x8*)(QpB + (size_t)((gt + m) * 2 + h) * 1024 + fragoff);

    f32x4 o[2][4];
    f32x4 lsum[2];
#pragma unroll
    for (int m = 0; m < 2; m++) {
        lsum[m] = (f32x4)(0.0f);
#pragma unroll
        for (int t = 0; t < 4; t++) o[m][t] = (f32x4)(0.0f);
    }

    for (int c = wave; c <= ti; c += 8) {
        const char* kb = KpB + (size_t)(c0 + c) * 4096;
        const char* vb = VpB + (size_t)(c0 + c) * 4096;
        bf16x8 bk[2][2], bv[4];
#pragma unroll
        for (int j = 0; j < 2; j++)
#pragma unroll
            for (int h = 0; h < 2; h++)
                bk[j][h] = *(const bf16x8*)(kb + j * 2048 + h * 1024 + fragoff);
#pragma unroll
        for (int t = 0; t < 4; t++)
            bv[t] = *(const bf16x8*)(vb + t * 1024 + fragoff);

        f32x4 s[2][2];
#pragma unroll
        for (int m = 0; m < 2; m++)
#pragma unroll
            for (int j = 0; j < 2; j++) {
                f32x4 a = MFMA16(aq[m][0], bk[j][0], (f32x4)(0.0f), 0, 0, 0);
                s[m][j] = MFMA16(aq[m][1], bk[j][1], a, 0, 0, 0);
            }
        const bool diag = (c == ti);
#pragma unroll
        for (int m = 0; m < 2; m++)
#pragma unroll
            for (int j = 0; j < 2; j++)
#pragma unroll
                for (int r = 0; r < 4; r++) {
                    float v = s[m][j][r];
                    if (diag && (j * 16 + col > m * 16 + quad * 4 + r)) v = -INFINITY;
                    const float p = __expf(v);   // |score| small: safe without max-sub
                    lsum[m][r] += p;
                    plds[wave][m][(quad * 4 + r) * 40 + j * 16 + col] =
                        (unsigned short)(__builtin_bit_cast(unsigned, p) >> 16);
                }
        bf16x8 pa[2];
#pragma unroll
        for (int m = 0; m < 2; m++)
            pa[m] = *(const bf16x8*)(&plds[wave][m][col * 40 + quad * 8]);
#pragma unroll
        for (int m = 0; m < 2; m++)
#pragma unroll
            for (int t = 0; t < 4; t++)
                o[m][t] = MFMA16(pa[m], bv[t], o[m][t], 0, 0, 0);
    }

    // staged tree reduction: 8 -> 4 -> 2 -> 1 partials
    auto wr = [&](int s) {
#pragma unroll
        for (int m = 0; m < 2; m++) {
#pragma unroll
            for (int t = 0; t < 4; t++)
                *(f32x4*)&cmb[s][m][lane][t * 4] = o[m][t];
            *(f32x4*)&cmb[s][m][lane][16] = lsum[m];
        }
    };
    auto rd = [&](int s) {
#pragma unroll
        for (int m = 0; m < 2; m++) {
#pragma unroll
            for (int t = 0; t < 4; t++)
                o[m][t] += *(const f32x4*)&cmb[s][m][lane][t * 4];
            lsum[m] += *(const f32x4*)&cmb[s][m][lane][16];
        }
    };
    if (wave >= 4) wr(wave - 4);
    __syncthreads();
    if (wave < 4) rd(wave);
    __syncthreads();
    if (wave == 2 || wave == 3) wr(wave);
    __syncthreads();
    if (wave < 2) rd(wave + 2);
    __syncthreads();
    if (wave == 1) wr(1);
    __syncthreads();
    if (wave == 0) {
        rd(1);
#pragma unroll
        for (int off = 1; off < 16; off <<= 1)
#pragma unroll
            for (int m = 0; m < 2; m++)
#pragma unroll
                for (int r = 0; r < 4; r++)
                    lsum[m][r] += __shfl_xor(lsum[m][r], off, 64);
#pragma unroll
        for (int m = 0; m < 2; m++)
#pragma unroll
            for (int r = 0; r < 4; r++) {
                const float inv = 1.0f / lsum[m][r];
                const size_t orow = (bT + q0 + m * 16 + quad * 4 + r) * HD;
#pragma unroll
                for (int t = 0; t < 4; t++)
                    Out[orow + t * 16 + col] = o[m][t][r] * inv;
            }
    }
}

extern "C" void kernel_launch(void* const* d_in, const int* in_sizes, int n_in,
                              void* d_out, int out_size, void* d_ws, size_t ws_size,
                              hipStream_t stream) {
    const float* x  = (const float*)d_in[0];
    const float* Wq = (const float*)d_in[1];
    const float* Wk = (const float*)d_in[2];
    const float* Wv = (const float*)d_in[3];
    float* out = (float*)d_out;

    char* w = (char*)d_ws;
    unsigned short* Wp = (unsigned short*)(w);                            // 384 KB
    unsigned short* Qp = (unsigned short*)(w + (512 << 10));              // 2 MB
    unsigned short* Kp = (unsigned short*)(w + (512 << 10) + (2 << 20));  // 2 MB
    unsigned short* Vp = (unsigned short*)(w + (512 << 10) + (4 << 20));  // 2 MB

    hipLaunchKernelGGL(prep_w, dim3(768), dim3(256), 0, stream, Wq, Wk, Wv, Wp);
    hipLaunchKernelGGL(proj_kernel, dim3(512), dim3(256), 0, stream, x, Wp, Qp, Kp, Vp);
    hipLaunchKernelGGL(attn_kernel, dim3(512), dim3(512), 0, stream, Qp, Kp, Vp, out);
}

// Round 9
// 159.531 us; speedup vs baseline: 1.2587x; 1.1307x over previous
//
#include <hip/hip_runtime.h>
#include <hip/hip_bf16.h>
#include <math.h>

typedef __attribute__((ext_vector_type(8))) short bf16x8;
typedef __attribute__((ext_vector_type(4))) float f32x4;

#define MFMA16 __builtin_amdgcn_mfma_f32_16x16x32_bf16

static constexpr int TSEQ = 4096;
static constexpr int EMB = 1024;

__device__ __forceinline__ unsigned short f2bf(float f) {
    unsigned u = __builtin_bit_cast(unsigned, f);
    u += 0x7fffu + ((u >> 16) & 1u);
    return (unsigned short)(u >> 16);
}
__device__ __forceinline__ int pk2bf(float a, float b) {
    return (int)((unsigned)f2bf(a) | ((unsigned)f2bf(b) << 16));
}

union frag_u { int i[4]; bf16x8 v; };

// W -> Wf[kc=32][group=12][16n x 32k frag, off = n*32 + k]. Wq pre-scaled 1/32.
__global__ void prep_w(const float* __restrict__ Wq, const float* __restrict__ Wk,
                       const float* __restrict__ Wv, unsigned short* __restrict__ Wf) {
    int id = blockIdx.x * 256 + threadIdx.x;        // 0..196607
    int wsel = id >> 16;
    int t = id & 65535;                             // k*64 + n0 (coalesced read)
    int k = t >> 6, n0 = t & 63;
    const float* W = (wsel == 0) ? Wq : (wsel == 1) ? Wk : Wv;
    float v = W[t];
    if (wsel == 0) v *= 0.03125f;                   // 1/sqrt(1024)
    int n = wsel * 64 + n0;
    Wf[(size_t)((k >> 5) * 12 + (n >> 4)) * 512 + (n & 15) * 32 + (k & 31)] = f2bf(v);
}

// X (fp32) -> Xf bf16, A-frag packed: Xf[tile=1024][kc=32][16m x 32k frag].
// Pure streaming pass; writes are dense 1KB/wave, reads 16x128B segments.
__global__ __launch_bounds__(256) void xpack(const float* __restrict__ X,
                                             unsigned short* __restrict__ Xf) {
    int t = blockIdx.x * 256 + threadIdx.x;         // 0..2M-1 (one 8-float octet each)
    int tile = t >> 11, rem = t & 2047;
    int kc = rem >> 6, s = rem & 63, row = s >> 2, k8 = s & 3;
    const float* xp = X + (size_t)(tile * 16 + row) * EMB + kc * 32 + k8 * 8;
    const float4 a = *(const float4*)(xp);
    const float4 b = *(const float4*)(xp + 4);
    frag_u u;
    u.i[0] = pk2bf(a.x, a.y); u.i[1] = pk2bf(a.z, a.w);
    u.i[2] = pk2bf(b.x, b.y); u.i[3] = pk2bf(b.z, b.w);
    *(bf16x8*)&Xf[((size_t)tile * 32 + kc) * 512 + row * 32 + k8 * 8] = u.v;
}

// Projection v7: 512 blocks x 4 waves; block = 32 rows, wave = col-quarter
// (2 row-frags x 3 col-frags, full K). NO LDS, NO barriers, NO conversion —
// all operands are lane-linear b128 loads from packed Xf/Wf; compiler free to
// overlap iterations. A-loads shared across the block's 4 waves via L1.
__global__ __launch_bounds__(256, 2) void proj_kernel(const unsigned short* __restrict__ Xf,
        const unsigned short* __restrict__ Wf, unsigned short* __restrict__ Qp,
        unsigned short* __restrict__ Kp, unsigned short* __restrict__ Vp) {
    const int lane = threadIdx.x & 63, wave = threadIdx.x >> 6;
    const int col = lane & 15, quad = lane >> 4;
    const int rp = blockIdx.x;
    const int lo = col * 32 + quad * 8;

    const unsigned short* a0b = Xf + (size_t)(rp * 2 + 0) * 32 * 512 + lo;
    const unsigned short* a1b = Xf + (size_t)(rp * 2 + 1) * 32 * 512 + lo;
    const unsigned short* wb  = Wf + (size_t)(wave * 3) * 512 + lo;

    f32x4 acc[2][3];
#pragma unroll
    for (int af = 0; af < 2; af++)
#pragma unroll
        for (int cf = 0; cf < 3; cf++) acc[af][cf] = (f32x4)(0.0f);

#pragma unroll 4
    for (int kc = 0; kc < 32; kc++) {
        const bf16x8 a0 = *(const bf16x8*)(a0b + kc * 512);
        const bf16x8 a1 = *(const bf16x8*)(a1b + kc * 512);
        const bf16x8 w0 = *(const bf16x8*)(wb + kc * 6144);
        const bf16x8 w1 = *(const bf16x8*)(wb + kc * 6144 + 512);
        const bf16x8 w2 = *(const bf16x8*)(wb + kc * 6144 + 1024);
        acc[0][0] = MFMA16(a0, w0, acc[0][0], 0, 0, 0);
        acc[1][0] = MFMA16(a1, w0, acc[1][0], 0, 0, 0);
        acc[0][1] = MFMA16(a0, w1, acc[0][1], 0, 0, 0);
        acc[1][1] = MFMA16(a1, w1, acc[1][1], 0, 0, 0);
        acc[0][2] = MFMA16(a0, w2, acc[0][2], 0, 0, 0);
        acc[1][2] = MFMA16(a1, w2, acc[1][2], 0, 0, 0);
    }

    // epilogue: wave-private packed Q/K/V writes (proven layouts)
    const int c = rp;
#pragma unroll
    for (int af = 0; af < 2; af++) {
        const int tile = c * 2 + af;
        const int j = af;
#pragma unroll
        for (int cf = 0; cf < 3; cf++) {
            const int n0 = wave * 48 + cf * 16;
            if (n0 < 64) {
                const int t = n0 >> 4;
#pragma unroll
                for (int r = 0; r < 4; r++)
                    Qp[tile * 1024 + (t >> 1) * 512 + (quad * 4 + r) * 32 +
                       ((t & 1) * 2 + (col >> 3)) * 8 + (col & 7)] = f2bf(acc[af][cf][r]);
            } else if (n0 < 128) {
                const int tt = (n0 - 64) >> 4;
#pragma unroll
                for (int r = 0; r < 4; r++)
                    Kp[((c * 2 + j) * 2 + (tt >> 1)) * 512 + (quad * 4 + r) * 32 +
                       ((tt & 1) * 2 + (col >> 3)) * 8 + (col & 7)] = f2bf(acc[af][cf][r]);
            } else {
                const int t4 = (n0 - 128) >> 4;
                ushort4 pk;
                pk.x = f2bf(acc[af][cf][0]); pk.y = f2bf(acc[af][cf][1]);
                pk.z = f2bf(acc[af][cf][2]); pk.w = f2bf(acc[af][cf][3]);
                *(ushort4*)&Vp[c * 2048 + t4 * 512 + col * 32 + j * 16 + quad * 4] = pk;
            }
        }
    }
}

// Flash attention v2: 1024 blocks = (batch, 16-row tile) heavy-first, 4 waves,
// chunks split 4 ways (fixed m=0 partials additive). K/V prefetch in two
// STATIC register sets; double-buffered wave-private P-LDS; 3-slot combine.
#define ATTN_PROCESS(K00, K01, K10, K11, V0, V1, V2, V3, CC, PB)                         \
    {                                                                                     \
        f32x4 s0 = MFMA16(aq0, K00, (f32x4)(0.0f), 0, 0, 0);                              \
        s0 = MFMA16(aq1, K01, s0, 0, 0, 0);                                               \
        f32x4 s1 = MFMA16(aq0, K10, (f32x4)(0.0f), 0, 0, 0);                              \
        s1 = MFMA16(aq1, K11, s1, 0, 0, 0);                                               \
        const bool diag = ((CC) == nch - 1);                                              \
        const int qrel = q0 - 32 * (CC) + quad * 4;                                       \
        unsigned short* pw = &plds[wave][PB][0];                                          \
        _Pragma("unroll") for (int r = 0; r < 4; r++) {                                   \
            float v0s = s0[r], v1s = s1[r];                                               \
            if (diag && (col > qrel + r)) v0s = -INFINITY;                                \
            if (diag && (16 + col > qrel + r)) v1s = -INFINITY;                           \
            const float p0 = __expf(v0s), p1 = __expf(v1s);                               \
            lsum[r] += p0 + p1;                                                           \
            pw[(quad * 4 + r) * 40 + col] =                                               \
                (unsigned short)(__builtin_bit_cast(unsigned, p0) >> 16);                 \
            pw[(quad * 4 + r) * 40 + 16 + col] =                                          \
                (unsigned short)(__builtin_bit_cast(unsigned, p1) >> 16);                 \
        }                                                                                 \
        const bf16x8 pa = *(const bf16x8*)(&pw[col * 40 + quad * 8]);                     \
        o[0] = MFMA16(pa, V0, o[0], 0, 0, 0);                                             \
        o[1] = MFMA16(pa, V1, o[1], 0, 0, 0);                                             \
        o[2] = MFMA16(pa, V2, o[2], 0, 0, 0);                                             \
        o[3] = MFMA16(pa, V3, o[3], 0, 0, 0);                                             \
    }

__global__ __launch_bounds__(256, 3) void attn_kernel(const unsigned short* __restrict__ Qp,
        const unsigned short* __restrict__ Kp, const unsigned short* __restrict__ Vp,
        float* __restrict__ Out) {
    __shared__ float cmb[3][64][20];               // 15 KB
    __shared__ unsigned short plds[4][2][640];     // 10 KB
    const int lane = threadIdx.x & 63, wave = threadIdx.x >> 6;
    const int col = lane & 15, quad = lane >> 4;
    const int batch = blockIdx.x & 3;
    const int ti = 255 - (blockIdx.x >> 2);
    const int q0 = ti * 16;
    const int nch = ((q0 + 15) >> 5) + 1;
    const int gt = batch * 256 + ti;
    const int c0 = batch * 128;
    const int lo = col * 32 + quad * 8;

    const bf16x8 aq0 = *(const bf16x8*)(Qp + (size_t)(gt * 2 + 0) * 512 + lo);
    const bf16x8 aq1 = *(const bf16x8*)(Qp + (size_t)(gt * 2 + 1) * 512 + lo);

    f32x4 o[4];
    f32x4 lsum = (f32x4)(0.0f);
#pragma unroll
    for (int t = 0; t < 4; t++) o[t] = (f32x4)(0.0f);

    // two static prefetch sets
    bf16x8 k00, k01, k10, k11, v0, v1, v2, v3;
    bf16x8 m00, m01, m10, m11, w0, w1, w2, w3;

#define LOAD_SET(K00, K01, K10, K11, V0, V1, V2, V3, CC)                      \
    {                                                                          \
        const unsigned short* kb = Kp + (size_t)(c0 + (CC)) * 2048 + lo;       \
        const unsigned short* vb = Vp + (size_t)(c0 + (CC)) * 2048 + lo;       \
        K00 = *(const bf16x8*)(kb);        K01 = *(const bf16x8*)(kb + 512);   \
        K10 = *(const bf16x8*)(kb + 1024); K11 = *(const bf16x8*)(kb + 1536);  \
        V0 = *(const bf16x8*)(vb);         V1 = *(const bf16x8*)(vb + 512);    \
        V2 = *(const bf16x8*)(vb + 1024);  V3 = *(const bf16x8*)(vb + 1536);   \
    }

    int c = wave;
    if (c < nch) LOAD_SET(k00, k01, k10, k11, v0, v1, v2, v3, c);
    while (c < nch) {
        if (c + 4 < nch) LOAD_SET(m00, m01, m10, m11, w0, w1, w2, w3, c + 4);
        ATTN_PROCESS(k00, k01, k10, k11, v0, v1, v2, v3, c, 0);
        c += 4;
        if (c >= nch) break;
        if (c + 4 < nch) LOAD_SET(k00, k01, k10, k11, v0, v1, v2, v3, c + 4);
        ATTN_PROCESS(m00, m01, m10, m11, w0, w1, w2, w3, c, 1);
        c += 4;
    }
#undef LOAD_SET

    if (wave) {
#pragma unroll
        for (int t = 0; t < 4; t++)
            *(f32x4*)&cmb[wave - 1][lane][t * 4] = o[t];
        *(f32x4*)&cmb[wave - 1][lane][16] = lsum;
    }
    __syncthreads();
    if (wave == 0) {
#pragma unroll
        for (int s = 0; s < 3; s++) {
#pragma unroll
            for (int t = 0; t < 4; t++)
                o[t] += *(const f32x4*)&cmb[s][lane][t * 4];
            lsum += *(const f32x4*)&cmb[s][lane][16];
        }
#pragma unroll
        for (int off = 1; off < 16; off <<= 1)
#pragma unroll
            for (int r = 0; r < 4; r++)
                lsum[r] += __shfl_xor(lsum[r], off, 64);
#pragma unroll
        for (int r = 0; r < 4; r++) {
            const float inv = 1.0f / lsum[r];
            const size_t orow = ((size_t)batch * TSEQ + q0 + quad * 4 + r) * 64;
#pragma unroll
            for (int t = 0; t < 4; t++)
                Out[orow + t * 16 + col] = o[t][r] * inv;
        }
    }
}

extern "C" void kernel_launch(void* const* d_in, const int* in_sizes, int n_in,
                              void* d_out, int out_size, void* d_ws, size_t ws_size,
                              hipStream_t stream) {
    const float* x  = (const float*)d_in[0];
    const float* Wq = (const float*)d_in[1];
    const float* Wk = (const float*)d_in[2];
    const float* Wv = (const float*)d_in[3];
    float* out = (float*)d_out;

    char* w = (char*)d_ws;
    unsigned short* Wf = (unsigned short*)(w);                            // 384 KB
    unsigned short* Qp = (unsigned short*)(w + (512 << 10));              // 2 MB
    unsigned short* Kp = (unsigned short*)(w + (512 << 10) + (2 << 20));  // 2 MB
    unsigned short* Vp = (unsigned short*)(w + (512 << 10) + (4 << 20));  // 2 MB
    unsigned short* Xf = (unsigned short*)(w + (8 << 20));                // 32 MB

    hipLaunchKernelGGL(prep_w, dim3(768), dim3(256), 0, stream, Wq, Wk, Wv, Wf);
    hipLaunchKernelGGL(xpack, dim3(8192), dim3(256), 0, stream, x, Xf);
    hipLaunchKernelGGL(proj_kernel, dim3(512), dim3(256), 0, stream, Xf, Wf, Qp, Kp, Vp);
    hipLaunchKernelGGL(attn_kernel, dim3(1024), dim3(256), 0, stream, Qp, Kp, Vp, out);
}